// Round 1
// baseline (271.317 us; speedup 1.0000x reference)
//
#include <hip/hip_runtime.h>
#include <math.h>

// Time2Vec: out[b,l,d,e] = (e==0) ? x[b,l,d]*W[d,0]+b[d,0]
//                                 : sin(x[b,l,d]*W[d,e]+b[d,e])
// B=32 L=4096 D=8 E=64. Output 256 MiB fp32, write-BW-bound (~45-55us floor).

#define T2V_E   64
#define T2V_DE  512   // D*E

__global__ __launch_bounds__(256) void t2v_kernel(
    const float* __restrict__ x,    // B*L*D elements
    const float* __restrict__ W,    // 512
    const float* __restrict__ bias, // 512
    float* __restrict__ out,        // B*L*D*E
    int n4)                         // number of float4 outputs
{
    __shared__ float4 sW[T2V_DE / 4];
    __shared__ float4 sB[T2V_DE / 4];
    const int t = threadIdx.x;
    if (t < T2V_DE / 4) {
        sW[t] = ((const float4*)W)[t];
        sB[t] = ((const float4*)bias)[t];
    }
    __syncthreads();

    const int stride = blockDim.x * gridDim.x;
    for (int i = blockIdx.x * blockDim.x + t; i < n4; i += stride) {
        const int i4 = i << 2;              // flat element index (max 67M, fits int)
        const float xv = x[i4 >> 6];        // one x per 64 outputs (E=64)
        const int wi = (i4 & (T2V_DE - 1)) >> 2;  // float4 index into W/b row-block
        const float4 w = sW[wi];
        const float4 c = sB[wi];
        float4 a;
        a.x = fmaf(xv, w.x, c.x);
        a.y = fmaf(xv, w.y, c.y);
        a.z = fmaf(xv, w.z, c.z);
        a.w = fmaf(xv, w.w, c.w);
        float4 o;
        // e==0 (identity, no sin) happens only at i4 % 64 == 0, on lane .x
        o.x = ((i4 & (T2V_E - 1)) == 0) ? a.x : __sinf(a.x);
        o.y = __sinf(a.y);
        o.z = __sinf(a.z);
        o.w = __sinf(a.w);
        ((float4*)out)[i] = o;
    }
}

extern "C" void kernel_launch(void* const* d_in, const int* in_sizes, int n_in,
                              void* d_out, int out_size, void* d_ws, size_t ws_size,
                              hipStream_t stream) {
    const float* x    = (const float*)d_in[0];
    const float* W    = (const float*)d_in[1];
    const float* bias = (const float*)d_in[2];
    float* out = (float*)d_out;

    const int n4 = out_size >> 2;           // out_size = 67108864, divisible by 4
    const int threads = 256;
    const int blocks = 8192;                // grid-stride; 32 blocks/CU worth queued
    t2v_kernel<<<blocks, threads, 0, stream>>>(x, W, bias, out, n4);
}

// Round 3
// 268.245 us; speedup vs baseline: 1.0115x; 1.0115x over previous
//
#include <hip/hip_runtime.h>
#include <math.h>

// Time2Vec: out[b,l,d,e] = (e==0) ? x[b,l,d]*W[d,0]+b[d,0]
//                                 : sin(x[b,l,d]*W[d,e]+b[d,e])
// B=32 L=4096 D=8 E=64. Output 256 MiB fp32 -> write-BW-bound.
// Floor: 268 MB / 6.5 TB/s (measured fill rate) ~= 41 us.

#define T2V_E   64
#define T2V_DE  512   // D*E

typedef float fx4 __attribute__((ext_vector_type(4)));  // native vec: OK for nontemporal builtin

__global__ __launch_bounds__(256) void t2v_kernel(
    const float* __restrict__ x,    // B*L*D
    const float* __restrict__ W,    // 512
    const float* __restrict__ bias, // 512
    fx4* __restrict__ out)          // B*L*D*E / 4 float4s
{
    __shared__ float4 sW[T2V_DE / 4];
    __shared__ float4 sB[T2V_DE / 4];
    const int t = threadIdx.x;
    if (t < T2V_DE / 4) {
        sW[t] = ((const float4*)W)[t];
        sB[t] = ((const float4*)bias)[t];
    }
    __syncthreads();

    // Each block covers 1024 consecutive float4s (4 per thread, stride 256).
    const int base = blockIdx.x * 1024 + t;   // float4 index of k=0

    // wi = i & 127 is identical for all 4 k (256 % 128 == 0): load W/b once.
    const int wi = (base & 127);
    const float4 w = sW[wi];
    const float4 c = sB[wi];

#pragma unroll
    for (int k = 0; k < 4; ++k) {
        const int i = base + k * 256;         // float4 index
        const float xv = x[i >> 4];           // 16 float4s per x element
        float ax = fmaf(xv, w.x, c.x);
        float ay = fmaf(xv, w.y, c.y);
        float az = fmaf(xv, w.z, c.z);
        float aw = fmaf(xv, w.w, c.w);
        fx4 o;
        o.x = ((i & 15) == 0) ? ax : __sinf(ax);  // e==0 only at i%16==0, lane .x
        o.y = __sinf(ay);
        o.z = __sinf(az);
        o.w = __sinf(aw);
        __builtin_nontemporal_store(o, &out[i]);
    }
}

extern "C" void kernel_launch(void* const* d_in, const int* in_sizes, int n_in,
                              void* d_out, int out_size, void* d_ws, size_t ws_size,
                              hipStream_t stream) {
    const float* x    = (const float*)d_in[0];
    const float* W    = (const float*)d_in[1];
    const float* bias = (const float*)d_in[2];
    fx4* out = (fx4*)d_out;

    // out_size = 67108864 floats = 16777216 float4 = 16384 blocks * 1024
    const int blocks = (out_size >> 2) / 1024;
    t2v_kernel<<<blocks, 256, 0, stream>>>(x, W, bias, out);
}